// Round 14
// baseline (73.770 us; speedup 1.0000x reference)
//
#include <hip/hip_runtime.h>

// Problem constants
#define MM 15   // max_peptide_size
#define RR 64   // aa_rep_size
#define PP 34   // pocket positions
#define FF 9    // filter size
#define AA 20   // alphabet size
#define OW 72   // RR + FF - 1
#define SP 84   // s_s row stride (floats), 16B-aligned
#define KS 12   // kernels row stride (floats), 16B-aligned

// One block per sample, 256 threads = 4 fully independent waves.
// ZERO __syncthreads: wave w owns rows p ≡ w (mod 4) end-to-end; shared
// tables (s_kern, s_idx) are staged redundantly by EVERY wave (identical
// values -> benign); one s_waitcnt lgkmcnt(0) orders each wave's own LDS
// writes before its reads (validated empirically in round 13).
__global__ __launch_bounds__(256)
void ppc_kernel(const float* __restrict__ pe,      // [B, M, R]
                const int*   __restrict__ idx,     // [B, P]
                const int*   __restrict__ adj,     // [B, P, M]
                const float* __restrict__ kernels, // [A, F]
                float*       __restrict__ out)     // [B, P, OW]
{
    const int b    = blockIdx.x;
    const int t    = threadIdx.x;
    const int lane = t & 63;
    const int w    = __builtin_amdgcn_readfirstlane(t >> 6);  // scalar wave id

    __shared__ float s_kern[AA * KS];  // 240 f
    __shared__ int   s_idx[PP];
    __shared__ float s_s[PP * SP];     // 2856 f
    // total ~12.6 KB

    const float* peb = pe + (size_t)b * (MM * RR);

    // per-lane pe column (same 3.8 KB for all 4 waves -> L1-shared)
    float pv[MM];
    #pragma unroll
    for (int m = 0; m < MM; ++m) pv[m] = peb[m * RR + lane];

    // ---- barrier-free staging (every wave writes identical values)
    if (lane < 60) {                       // 60*3 = 180 = AA*FF entries
        #pragma unroll
        for (int u = 0; u < 3; ++u) {
            const int i = lane * 3 + u;
            const int a = (unsigned)i / FF, j = i - a * FF;
            s_kern[a * KS + j] = kernels[i];
        }
    }
    if (lane < PP) s_idx[lane] = idx[(size_t)b * PP + lane];
    if (lane < 45) {                       // zero pads for THIS wave's rows
        const int j  = (unsigned)lane / 5, kk = lane - j * 5;
        const int p  = w + 4 * j;
        if (p < PP) {
            const int off = p * SP + (kk < 2 ? kk * 4 : 72 + (kk - 2) * 4);
            *(float4*)&s_s[off] = make_float4(0.f, 0.f, 0.f, 0.f);
        }
    }

    // ---- Phase B: rows p = w+4j; adj via SCALAR loads (b, p wave-uniform),
    // gates are 0/1 -> uniform-predicated adds (no cvt, ~50% skipped)
    const int* adjb = adj + (size_t)b * (PP * MM);
    #pragma unroll
    for (int j = 0; j < 9; ++j) {
        const int p = w + 4 * j;
        if (p < PP) {
            const int* g = adjb + p * MM;
            float acc = 0.f;
            #pragma unroll
            for (int m = 0; m < MM; ++m)
                if (g[m] != 0) acc += pv[m];
            s_s[p * SP + 8 + lane] = acc;  // consecutive dwords: 2-way, free
        }
    }

    // order this wave's LDS writes before its reads (no cross-wave deps)
    asm volatile("s_waitcnt lgkmcnt(0)" ::: "memory");

    // ---- Phase C: 3 passes; lane -> (rowk = lane/18, o0 = 4*(lane%18))
    float* outb = out + (size_t)b * (PP * OW);
    const int rowk = (unsigned)lane / 18u;       // 0..3 (3 = idle)
    const int o0   = (lane - 18 * rowk) << 2;    // 0..68

    #pragma unroll
    for (int k = 0; k < 3; ++k) {
        const int p = w + 12 * k + 4 * rowk;     // own rows only
        if (rowk < 3 && p < PP) {
            const float* kb = &s_kern[s_idx[p] * KS];   // group-uniform bcast
            const float4 k0 = *(const float4*)&kb[0];
            const float4 k1 = *(const float4*)&kb[4];
            float kf[FF] = {k0.x,k0.y,k0.z,k0.w, k1.x,k1.y,k1.z,k1.w, kb[8]};

            const float* row = &s_s[p * SP];
            float wv[12];
            *(float4*)&wv[0] = *(const float4*)&row[o0];      // aligned b128
            *(float4*)&wv[4] = *(const float4*)&row[o0 + 4];
            *(float4*)&wv[8] = *(const float4*)&row[o0 + 8];

            float ax=0, ay=0, az=0, aw=0;
            #pragma unroll
            for (int jj = 0; jj < FF; ++jj) {
                const float kk = kf[jj];
                ax += kk * wv[8  - jj];
                ay += kk * wv[9  - jj];
                az += kk * wv[10 - jj];
                aw += kk * wv[11 - jj];
            }
            *(float4*)&outb[p * OW + o0] = make_float4(ax, ay, az, aw);
        }
    }
}

extern "C" void kernel_launch(void* const* d_in, const int* in_sizes, int n_in,
                              void* d_out, int out_size, void* d_ws, size_t ws_size,
                              hipStream_t stream) {
    const float* pe      = (const float*)d_in[0]; // [B,M,R] f32
    const int*   idx     = (const int*)  d_in[1]; // [B,P]   i32
    const int*   adj     = (const int*)  d_in[2]; // [B,P,M] i32
    const float* kernels = (const float*)d_in[3]; // [A,F]   f32
    float*       out     = (float*)d_out;

    const int B = in_sizes[0] / (MM * RR);
    ppc_kernel<<<B, 256, 0, stream>>>(pe, idx, adj, kernels, out);
}